// Round 8
// baseline (871.130 us; speedup 1.0000x reference)
//
#include <hip/hip_runtime.h>

#define NN 100000
#define NE 1600000
#define NF 128
#define NH 64
#define NK 20
#define SBK 192                     // nodes per bucket (LDS acc tile)
#define NSB ((NN + SBK - 1) / SBK)  // 521 buckets
#define CT 4096                     // edges per coarse-scatter block
#define AGW 16                      // waves in k_agg block

static constexpr float ALPHA = 0.2f;

typedef unsigned short u16;
typedef unsigned int u32;

// ---- workspace layout (aligned to 256B) ----
constexpr size_t alup(size_t x) { return (x + 255) & ~size_t(255); }
constexpr size_t O_FLAG   = 0;                                    // 4 B
constexpr size_t O_DINV   = 256;                                  // NN f32
constexpr size_t O_GBH    = alup(O_DINV + size_t(NN) * 4);        // NSB i32 (bucket edge counts)
constexpr size_t O_BBASE  = alup(O_GBH  + size_t(NSB) * 4);       // NSB+1 i32
constexpr size_t O_BCUR   = alup(O_BBASE + size_t(NSB + 1) * 4);  // NSB i32
constexpr size_t O_COARSE = alup(O_BCUR + size_t(NSB) * 4);       // NE uint2 (12.8 MB) bucket-grouped
constexpr size_t O_SUP    = alup(O_COARSE + size_t(NE) * 8);      // NN*NH bf16 (12.8 MB), dinv-scaled x@W
// total ~ 26 MB

__device__ __forceinline__ u16 f2bf(float f) {   // RNE float->bf16
  u32 u = __float_as_uint(f);
  u32 r = (u + 0x7fffu + ((u >> 16) & 1u)) >> 16;
  return (u16)r;
}
__device__ __forceinline__ float bf2f(u16 h) {
  return __uint_as_float(((u32)h) << 16);
}

// edge_index dtype probe + zero the bucket histogram.
__global__ __launch_bounds__(256) void k_detect(const void* ei, int* flag, int* gbh) {
  __shared__ int bad;
  if (threadIdx.x == 0) bad = 0;
  for (int i = threadIdx.x; i < NSB; i += 256) gbh[i] = 0;
  __syncthreads();
  const long long* p = (const long long*)ei;
  int ok = 1;
#pragma unroll
  for (int k = 0; k < 4; ++k) {
    long long v = p[threadIdx.x * 4 + k];
    if (v < 0 || v >= NN) ok = 0;
  }
  if (!ok) atomicOr(&bad, 1);
  __syncthreads();
  if (threadIdx.x == 0) *flag = bad ? 0 : 1;
}

// bucket histogram (521 bins) via LDS, one global atomic per bin per block.
__global__ __launch_bounds__(256) void k_bhist(const void* ei, const int* __restrict__ flag,
                                               int* gbh) {
  __shared__ int lh[NSB];
  int t = threadIdx.x;
  for (int i = t; i < NSB; i += 256) lh[i] = 0;
  __syncthreads();
  int base = blockIdx.x * CT;
  int is64 = *flag;
#pragma unroll
  for (int k = 0; k < 16; ++k) {
    int e = base + k * 256 + t;
    if (e < NE) {
      int d;
      if (is64) d = (int)((const long long*)ei)[NE + e];
      else      d = ((const int*)ei)[NE + e];
      atomicAdd(&lh[d / SBK], 1);
    }
  }
  __syncthreads();
  for (int i = t; i < NSB; i += 256) { int c = lh[i]; if (c) atomicAdd(&gbh[i], c); }
}

// exclusive scan of 521 bucket edge-counts (single 1024-thread block).
__global__ __launch_bounds__(1024) void k_bscan(const int* __restrict__ gbh,
                                                int* bbase, int* bcur) {
  __shared__ int sh[1024];
  int t = threadIdx.x;
  int v = (t < NSB) ? gbh[t] : 0;
  sh[t] = v;
  __syncthreads();
  int a = v;
  for (int d = 1; d < 1024; d <<= 1) {
    int add = (t >= d) ? sh[t - d] : 0;
    __syncthreads();
    a += add; sh[t] = a;
    __syncthreads();
  }
  int excl = a - v;
  if (t < NSB) { bbase[t] = excl; bcur[t] = excl; }
  if (t == NSB - 1) bbase[NSB] = excl + v;   // = NE
}

// coarse scatter: bin edges by dst-bucket; LDS ranking makes each block's
// same-bucket writes contiguous -> bucket frontier stays in L2.
__global__ __launch_bounds__(256) void k_coarse(const void* ei, const int* __restrict__ flag,
                                                const float* __restrict__ w,
                                                int* bcur, uint2* __restrict__ coarse) {
  __shared__ int lh[NSB];
  __shared__ int lbase[NSB];
  int t = threadIdx.x;
  for (int i = t; i < NSB; i += 256) lh[i] = 0;
  __syncthreads();
  int base = blockIdx.x * CT;
  int is64 = *flag;
  u32 key[16]; int wb[16], bk[16], lr[16];
#pragma unroll
  for (int k = 0; k < 16; ++k) {
    int e = base + k * 256 + t;
    if (e < NE) {
      int s, d;
      if (is64) { const long long* p = (const long long*)ei; s = (int)p[e]; d = (int)p[NE + e]; }
      else      { const int*       p = (const int*)ei;       s = p[e];      d = p[NE + e]; }
      int bb = d / SBK, dlo = d - bb * SBK;
      key[k] = (u32)s | ((u32)dlo << 17);     // src:17 bits | dlo:8 bits
      wb[k]  = __float_as_int(w[e]);
      bk[k]  = bb;
      lr[k]  = atomicAdd(&lh[bb], 1);
    }
  }
  __syncthreads();
  for (int i = t; i < NSB; i += 256) { int c = lh[i]; if (c) lbase[i] = atomicAdd(&bcur[i], c); }
  __syncthreads();
#pragma unroll
  for (int k = 0; k < 16; ++k) {
    int e = base + k * 256 + t;
    if (e < NE) coarse[lbase[bk[k]] + lr[k]] = make_uint2(key[k], (u32)wb[k]);
  }
}

// weighted degree per node from bucket-grouped coarse -> dinv.
__global__ __launch_bounds__(256) void k_dinvb(const uint2* __restrict__ coarse,
                                               const int* __restrict__ bbase,
                                               float* __restrict__ dinv) {
  __shared__ float wsum[SBK];
  int t = threadIdx.x, blk = blockIdx.x;
  for (int i = t; i < SBK; i += 256) wsum[i] = 0.f;
  __syncthreads();
  int s = bbase[blk], e = bbase[blk + 1];
  for (int j = s + t; j < e; j += 256) {
    uint2 u = coarse[j];
    atomicAdd(&wsum[u.x >> 17], __uint_as_float(u.y));
  }
  __syncthreads();
  for (int i = t; i < SBK; i += 256) {
    int node = blk * SBK + i;
    if (node < NN) dinv[node] = rsqrtf(1.0f + wsum[i]);   // +1 = self-loop
  }
}

// sup = bf16( dinv[:,None] * (x @ W) ) ; W (32KB) staged in LDS.
__global__ __launch_bounds__(256) void k_gemm(const float* __restrict__ x,
                                              const float* __restrict__ W,
                                              const float* __restrict__ dinv,
                                              u16* __restrict__ supb) {
  __shared__ float4 Wl[NF * NH / 4];
  const float4* Wg = (const float4*)W;
  for (int i = threadIdx.x; i < NF * NH / 4; i += 256) Wl[i] = Wg[i];
  __syncthreads();
  int lane16 = threadIdx.x & 15;
  int rowin  = threadIdx.x >> 4;
  const float4* x4 = (const float4*)x;
  int rowbase = blockIdx.x * 128;
  for (int r0 = 0; r0 < 128; r0 += 16) {
    int r = rowbase + r0 + rowin;
    if (r >= NN) return;
    float4 acc = make_float4(0.f, 0.f, 0.f, 0.f);
#pragma unroll 8
    for (int kk = 0; kk < NF / 4; ++kk) {
      float4 xv = x4[r * (NF / 4) + kk];
      float4 w0 = Wl[(4 * kk + 0) * 16 + lane16];
      float4 w1 = Wl[(4 * kk + 1) * 16 + lane16];
      float4 w2 = Wl[(4 * kk + 2) * 16 + lane16];
      float4 w3 = Wl[(4 * kk + 3) * 16 + lane16];
      acc.x += xv.x * w0.x + xv.y * w1.x + xv.z * w2.x + xv.w * w3.x;
      acc.y += xv.x * w0.y + xv.y * w1.y + xv.z * w2.y + xv.w * w3.y;
      acc.z += xv.x * w0.z + xv.y * w1.z + xv.z * w2.z + xv.w * w3.z;
      acc.w += xv.x * w0.w + xv.y * w1.w + xv.z * w2.w + xv.w * w3.w;
    }
    float di = dinv[r];
    ushort4 o;
    o.x = f2bf(acc.x * di); o.y = f2bf(acc.y * di);
    o.z = f2bf(acc.z * di); o.w = f2bf(acc.w * di);
    *(ushort4*)&supb[(size_t)r * NH + lane16 * 4] = o;
  }
}

// Bucket-resident aggregation + head. One block per 192-node bucket:
// acc[192][65] f32 in LDS (stride 65 => row AND column access conflict-free).
// Phase 1: init acc rows with self-loop term. Phase 2: stream bucket edges,
// gather sup row, ds_add_f32 into acc (64 consecutive addrs = free 2-way).
// Phase 3 (transposed, lane=node): z = di*acc+b, d2[k] in VGPRs (no cross-lane
// reduction at all), z re-transposed through acc for coalesced stores.
__global__ __launch_bounds__(1024, 8) void k_agg(const uint2* __restrict__ coarse,
                                                 const int* __restrict__ bbase,
                                                 const float* __restrict__ dinv,
                                                 const u16* __restrict__ supb,
                                                 const float* __restrict__ b,
                                                 const float* __restrict__ mu,
                                                 float* __restrict__ z,
                                                 float* __restrict__ q) {
  __shared__ float acc[SBK][65];
  __shared__ float muT[64][20];
  __shared__ float bL[64];
  int t = threadIdx.x, blk = blockIdx.x;
  int lane = t & 63, wv = t >> 6;
  int nbase = blk * SBK;

  for (int i = t; i < NK * NH; i += 1024) muT[i & 63][i >> 6] = mu[i];  // mu[k][f]->muT[f][k]
  if (t < 64) bL[t] = b[t];
  for (int i = wv; i < SBK; i += AGW) {
    int node = nbase + i;
    acc[i][lane] = (node < NN) ? bf2f(supb[(size_t)node * NH + lane]) : 0.f;
  }
  __syncthreads();

  int s = bbase[blk], e = bbase[blk + 1];
  int j0 = s + wv * 8;
  for (; j0 + 8 <= e; j0 += AGW * 8) {
    uint2 u0 = coarse[j0 + 0], u1 = coarse[j0 + 1], u2 = coarse[j0 + 2], u3 = coarse[j0 + 3];
    uint2 u4 = coarse[j0 + 4], u5 = coarse[j0 + 5], u6 = coarse[j0 + 6], u7 = coarse[j0 + 7];
    float v0 = bf2f(supb[(size_t)(u0.x & 0x1FFFFu) * NH + lane]);
    float v1 = bf2f(supb[(size_t)(u1.x & 0x1FFFFu) * NH + lane]);
    float v2 = bf2f(supb[(size_t)(u2.x & 0x1FFFFu) * NH + lane]);
    float v3 = bf2f(supb[(size_t)(u3.x & 0x1FFFFu) * NH + lane]);
    float v4 = bf2f(supb[(size_t)(u4.x & 0x1FFFFu) * NH + lane]);
    float v5 = bf2f(supb[(size_t)(u5.x & 0x1FFFFu) * NH + lane]);
    float v6 = bf2f(supb[(size_t)(u6.x & 0x1FFFFu) * NH + lane]);
    float v7 = bf2f(supb[(size_t)(u7.x & 0x1FFFFu) * NH + lane]);
    atomicAdd(&acc[u0.x >> 17][lane], __uint_as_float(u0.y) * v0);
    atomicAdd(&acc[u1.x >> 17][lane], __uint_as_float(u1.y) * v1);
    atomicAdd(&acc[u2.x >> 17][lane], __uint_as_float(u2.y) * v2);
    atomicAdd(&acc[u3.x >> 17][lane], __uint_as_float(u3.y) * v3);
    atomicAdd(&acc[u4.x >> 17][lane], __uint_as_float(u4.y) * v4);
    atomicAdd(&acc[u5.x >> 17][lane], __uint_as_float(u5.y) * v5);
    atomicAdd(&acc[u6.x >> 17][lane], __uint_as_float(u6.y) * v6);
    atomicAdd(&acc[u7.x >> 17][lane], __uint_as_float(u7.y) * v7);
  }
  if (j0 < e) {
    for (int j = j0; j < e; ++j) {
      uint2 u = coarse[j];
      float v = bf2f(supb[(size_t)(u.x & 0x1FFFFu) * NH + lane]);
      atomicAdd(&acc[u.x >> 17][lane], __uint_as_float(u.y) * v);
    }
  }
  __syncthreads();

  if (wv < SBK / 64) {                      // 3 epilogue waves, lane = node
    int row  = wv * 64 + lane;
    int node = nbase + row;
    float di = (node < NN) ? dinv[node] : 0.f;
    float d2[NK];
#pragma unroll
    for (int k = 0; k < NK; ++k) d2[k] = 0.f;
    for (int f = 0; f < 64; ++f) {
      float zf = di * acc[row][f] + bL[f];  // lane stride 65 -> conflict-free
      acc[row][f] = zf;                     // stash for coalesced z store
#pragma unroll
      for (int k = 0; k < NK; ++k) {
        float dd = zf - muT[f][k];          // broadcast LDS reads
        d2[k] += dd * dd;
      }
    }
    // coalesced z store (same-wave DS ops are in order; no barrier needed)
    int grp = nbase + wv * 64;
    for (int n2 = 0; n2 < 64; ++n2) {
      int node2 = grp + n2;
      if (node2 < NN) z[(size_t)node2 * NH + lane] = acc[wv * 64 + n2][lane];
    }
    // q: everything per-lane, zero cross-lane ops
    float ssum = 0.f;
#pragma unroll
    for (int k = 0; k < NK; ++k) {
      float tq = 1.0f / (1.0f + d2[k] * (1.0f / ALPHA) + 1e-8f);
      float qe = exp2f((ALPHA + 1.0f) * __log2f(tq));
      d2[k] = qe; ssum += qe;
    }
    float rs = 1.0f / ssum;
    if (node < NN) {
#pragma unroll
      for (int k = 0; k < NK; ++k) q[(size_t)node * NK + k] = d2[k] * rs;
    }
  }
}

extern "C" void kernel_launch(void* const* d_in, const int* in_sizes, int n_in,
                              void* d_out, int out_size, void* d_ws, size_t ws_size,
                              hipStream_t stream) {
  const float* x  = (const float*)d_in[0];
  const void*  ei = d_in[1];
  const float* w  = (const float*)d_in[2];
  const float* W  = (const float*)d_in[3];
  const float* b  = (const float*)d_in[4];
  const float* mu = (const float*)d_in[5];

  char* ws = (char*)d_ws;
  int*   flag   = (int*)(ws + O_FLAG);
  float* dinv   = (float*)(ws + O_DINV);
  int*   gbh    = (int*)(ws + O_GBH);
  int*   bbase  = (int*)(ws + O_BBASE);
  int*   bcur   = (int*)(ws + O_BCUR);
  uint2* coarse = (uint2*)(ws + O_COARSE);
  u16*   supb   = (u16*)(ws + O_SUP);

  float* z = (float*)d_out;
  float* q = (float*)d_out + (size_t)NN * NH;

  hipLaunchKernelGGL(k_detect, dim3(1),                  dim3(256),  0, stream, ei, flag, gbh);
  hipLaunchKernelGGL(k_bhist,  dim3((NE + CT - 1) / CT), dim3(256),  0, stream, ei, flag, gbh);
  hipLaunchKernelGGL(k_bscan,  dim3(1),                  dim3(1024), 0, stream, gbh, bbase, bcur);
  hipLaunchKernelGGL(k_coarse, dim3((NE + CT - 1) / CT), dim3(256),  0, stream, ei, flag, w, bcur, coarse);
  hipLaunchKernelGGL(k_dinvb,  dim3(NSB),                dim3(256),  0, stream, coarse, bbase, dinv);
  hipLaunchKernelGGL(k_gemm,   dim3((NN + 127) / 128),   dim3(256),  0, stream, x, W, dinv, supb);
  hipLaunchKernelGGL(k_agg,    dim3(NSB),                dim3(1024), 0, stream, coarse, bbase, dinv, supb, b, mu, z, q);
}